// Round 21
// baseline (1675.087 us; speedup 1.0000x reference)
//
#include <hip/hip_runtime.h>

#define HD 100
#define NF 16
#define EF 8
#define NN 50000
#define NE 400000
#define NT64 6250   // NE/64 tiles

typedef __attribute__((ext_vector_type(8))) short bf16x8;
typedef __attribute__((ext_vector_type(4))) float f32x4;

__device__ __forceinline__ float frelu(float v) { return v > 0.f ? v : 0.f; }
__device__ __forceinline__ unsigned short f2bf(float f) {
  unsigned int u = __float_as_uint(f);
  unsigned int r = (u + 0x7FFF + ((u >> 16) & 1)) >> 16;   // RNE
  return (unsigned short)r;
}
// XOR-swizzle: spread bank-aligned rows across 16B slots (G4 / T2)
__device__ __forceinline__ int SWZ(int row, int byte) { return byte ^ ((row & 7) << 4); }
__device__ __forceinline__ float4 L4(const float* p) { return *(const float4*)p; }
__device__ __forceinline__ uint2 pk4(float4 f) {
  uint2 o;
  o.x = (unsigned)f2bf(f.x) | ((unsigned)f2bf(f.y) << 16);
  o.y = (unsigned)f2bf(f.z) | ((unsigned)f2bf(f.w) << 16);
  return o;
}

// ---------------- weight pre-pack: W[K][N] fp32 -> frag-linear bf16 ----------------
__device__ __forceinline__ void pack_one(const float* __restrict__ W,
    unsigned short* __restrict__ out, int K, int N, int NT, int t) {
  int lane = t & 63, nt = (t >> 6) % NT, ks = (t >> 6) / NT;
  int kb = ks * 32 + (lane >> 4) * 8, n = nt * 16 + (lane & 15);
  unsigned short v[8];
  #pragma unroll
  for (int j = 0; j < 8; ++j) {
    int k = kb + j;
    float f = (k < K && n < N) ? W[(size_t)k * N + n] : 0.f;
    v[j] = f2bf(f);
  }
  uint4 o4;
  o4.x = (unsigned)v[0] | ((unsigned)v[1] << 16);
  o4.y = (unsigned)v[2] | ((unsigned)v[3] << 16);
  o4.z = (unsigned)v[4] | ((unsigned)v[5] << 16);
  o4.w = (unsigned)v[6] | ((unsigned)v[7] << 16);
  *(uint4*)&out[(size_t)t * 8] = o4;
}

// one launch packs all 5 weight matrices (both layers' W1/W2 + final W1)
__global__ __launch_bounds__(256) void k_pack_all(
    const float* __restrict__ em_w1, const float* __restrict__ em_w2,
    const float* __restrict__ mlp_w1,
    unsigned short* __restrict__ w1p0, unsigned short* __restrict__ w1p1,
    unsigned short* __restrict__ w2p0, unsigned short* __restrict__ w2p1,
    unsigned short* __restrict__ wf1p) {
  int t = blockIdx.x * 256 + threadIdx.x;
  if (t < 4480)        pack_one(em_w1,          w1p0, 300, 100, 7, t);
  else if (t < 8960)   pack_one(em_w1 + 30000,  w1p1, 300, 100, 7, t - 4480);
  else if (t < 10752)  pack_one(em_w2,          w2p0, 100, 100, 7, t - 8960);
  else if (t < 12544)  pack_one(em_w2 + 10000,  w2p1, 100, 100, 7, t - 10752);
  else if (t < 15104)  pack_one(mlp_w1,         wf1p, 300, 50, 4, t - 12544);
}

__global__ __launch_bounds__(256) void k_node_embed(const float* __restrict__ x,
    const float* __restrict__ w, const float* __restrict__ b, float* __restrict__ h) {
  int t = blockIdx.x * 256 + threadIdx.x;
  int n = t / HD, o = t % HD;
  if (n >= NN) return;
  float acc = b[o];
  #pragma unroll
  for (int k = 0; k < NF; ++k) acc = fmaf(x[n * NF + k], w[k * HD + o], acc);
  h[(size_t)n * HD + o] = acc;
}

// e stored in PERMUTED (dst-sorted) layout
__global__ __launch_bounds__(256) void k_edge_embed_perm(const float* __restrict__ ea,
    const int* __restrict__ eids, const float* __restrict__ w, const float* __restrict__ b,
    float* __restrict__ e) {
  __shared__ float ws_[EF * HD];
  __shared__ float bs_[HD];
  int tid = threadIdx.x;
  for (int i = tid; i < EF * HD; i += 256) ws_[i] = w[i];
  for (int i = tid; i < HD; i += 256) bs_[i] = b[i];
  __syncthreads();
  long long t = (long long)blockIdx.x * 256 + tid;
  int p = (int)(t / 25), c4 = (int)(t % 25);
  if (p >= NE) return;
  int eid = eids[p];
  const float* ap = ea + (size_t)eid * EF;
  float4 a0 = L4(ap), a1 = L4(ap + 4);
  float av[8] = {a0.x, a0.y, a0.z, a0.w, a1.x, a1.y, a1.z, a1.w};
  int c0 = c4 * 4;
  float o0 = bs_[c0], o1 = bs_[c0 + 1], o2 = bs_[c0 + 2], o3 = bs_[c0 + 3];
  #pragma unroll
  for (int k = 0; k < EF; ++k) {
    const float* wr = &ws_[k * HD + c0];
    o0 = fmaf(av[k], wr[0], o0); o1 = fmaf(av[k], wr[1], o1);
    o2 = fmaf(av[k], wr[2], o2); o3 = fmaf(av[k], wr[3], o3);
  }
  float4 o; o.x = o0; o.y = o1; o.z = o2; o.w = o3;
  ((float4*)e)[(size_t)p * 25 + c4] = o;
}

// ---------------- CSR build ----------------
__global__ __launch_bounds__(256) void k_hist(const int* __restrict__ dst, int* __restrict__ deg) {
  int eid = blockIdx.x * 256 + threadIdx.x;
  if (eid < NE) atomicAdd(&deg[dst[eid]], 1);
}
__global__ __launch_bounds__(256) void k_scan_part(const int* __restrict__ deg, int* __restrict__ part) {
  __shared__ int sm[256];
  int i = blockIdx.x * 256 + threadIdx.x;
  sm[threadIdx.x] = (i < NN) ? deg[i] : 0;
  __syncthreads();
  for (int s = 128; s > 0; s >>= 1) {
    if (threadIdx.x < s) sm[threadIdx.x] += sm[threadIdx.x + s];
    __syncthreads();
  }
  if (threadIdx.x == 0) part[blockIdx.x] = sm[0];
}
__global__ __launch_bounds__(256) void k_scan_top(int* __restrict__ part, int nb) {
  __shared__ int sm[256];
  int v = (threadIdx.x < nb) ? part[threadIdx.x] : 0;
  sm[threadIdx.x] = v;
  __syncthreads();
  for (int off = 1; off < 256; off <<= 1) {
    int t = (threadIdx.x >= (unsigned)off) ? sm[threadIdx.x - off] : 0;
    __syncthreads();
    sm[threadIdx.x] += t;
    __syncthreads();
  }
  if (threadIdx.x < nb) part[threadIdx.x] = sm[threadIdx.x] - v;  // exclusive
}
// writes BOTH rowptr and cursor (cursor = rowptr[0..NN-1])
__global__ __launch_bounds__(256) void k_scan_fill(const int* __restrict__ deg,
    const int* __restrict__ part, int* __restrict__ rowptr, int* __restrict__ cursor) {
  __shared__ int sm[256];
  int i = blockIdx.x * 256 + threadIdx.x;
  int v = (i < NN) ? deg[i] : 0;
  sm[threadIdx.x] = v;
  __syncthreads();
  for (int off = 1; off < 256; off <<= 1) {
    int t = (threadIdx.x >= (unsigned)off) ? sm[threadIdx.x - off] : 0;
    __syncthreads();
    sm[threadIdx.x] += t;
    __syncthreads();
  }
  int pfx = part[blockIdx.x] + sm[threadIdx.x] - v;  // exclusive prefix
  if (i <= NN) rowptr[i] = pfx;
  if (i < NN) cursor[i] = pfx;
}
__global__ __launch_bounds__(256) void k_fill(const int* __restrict__ dst,
    int* __restrict__ cursor, int* __restrict__ eids) {
  int eid = blockIdx.x * 256 + threadIdx.x;
  if (eid >= NE) return;
  int pos = atomicAdd(&cursor[dst[eid]], 1);
  eids[pos] = eid;
}

// ---- FUSED gather + node update (round-17 proven) ----
__global__ __launch_bounds__(256) void k_gather_node(
    float* __restrict__ h, const float* __restrict__ e,
    const int* __restrict__ rowptr, const int* __restrict__ eids,
    const int* __restrict__ src,
    const float* __restrict__ w1, const float* __restrict__ b1,
    const float* __restrict__ w2, const float* __restrict__ b2,
    const float* __restrict__ gamma, const float* __restrict__ beta) {
  __shared__ float zs[64 * 101];
  int tid = threadIdx.x;
  int base = blockIdx.x * 64;
  {
    int slot = tid >> 2, sub = tid & 3;
    int n = base + slot;
    int cn = n < NN ? n : NN - 1;
    int r0 = rowptr[cn], r1 = rowptr[cn + 1];
    float4 acc[7];
    #pragma unroll
    for (int i = 0; i < 7; ++i) { acc[i].x = 0.f; acc[i].y = 0.f; acc[i].z = 0.f; acc[i].w = 0.f; }
    for (int p = r0; p < r1; ++p) {
      int s = src[eids[p]];
      const float4* hp = (const float4*)&h[(size_t)s * HD];
      const float4* ep = (const float4*)&e[(size_t)p * HD];
      #pragma unroll
      for (int i = 0; i < 7; ++i) {
        int c = sub + i * 4;
        if (c < 25) {
          float4 hv = hp[c], ev = ep[c];
          acc[i].x += frelu(hv.x + ev.x);
          acc[i].y += frelu(hv.y + ev.y);
          acc[i].z += frelu(hv.z + ev.z);
          acc[i].w += frelu(hv.w + ev.w);
        }
      }
    }
    const float4* hn = (const float4*)&h[(size_t)cn * HD];
    #pragma unroll
    for (int i = 0; i < 7; ++i) {
      int c = sub + i * 4;
      if (c < 25) {
        float4 hv = hn[c];
        float* zp = &zs[slot * 101 + c * 4];
        zp[0] = hv.x + acc[i].x;
        zp[1] = hv.y + acc[i].y;
        zp[2] = hv.z + acc[i].z;
        zp[3] = hv.w + acc[i].w;
      }
    }
  }
  __syncthreads();
  int el = tid & 63;
  int o0 = __builtin_amdgcn_readfirstlane((tid >> 6) * 25);
  float* row = &zs[el * 101];
  float acc[25];
  #pragma unroll
  for (int j = 0; j < 25; ++j) acc[j] = b1[o0 + j];
  for (int k = 0; k < HD; ++k) {
    float a = row[k];
    const float* wr = &w1[k * HD + o0];
    #pragma unroll
    for (int j = 0; j < 25; ++j) acc[j] = fmaf(a, wr[j], acc[j]);
  }
  __syncthreads();
  #pragma unroll
  for (int j = 0; j < 25; ++j) row[o0 + j] = frelu(acc[j]);
  __syncthreads();
  float acc2[25];
  #pragma unroll
  for (int j = 0; j < 25; ++j) acc2[j] = b2[o0 + j];
  for (int k = 0; k < HD; ++k) {
    float a = row[k];
    const float* wr = &w2[k * HD + o0];
    #pragma unroll
    for (int j = 0; j < 25; ++j) acc2[j] = fmaf(a, wr[j], acc2[j]);
  }
  int gn = base + el;
  if (gn < NN) {
    const float bninv = 0.99999500003749973f;  // 1/sqrt(1+1e-5)
    #pragma unroll
    for (int j = 0; j < 25; ++j) {
      int o = o0 + j;
      float bn = acc2[j] * (gamma[o] * bninv) + beta[o];
      h[(size_t)gn * HD + o] = (h[(size_t)gn * HD + o] + frelu(bn)) * 0.5f;
    }
  }
}

// ---- layer-1 edge update: 1024 thr / 16 waves, 4 N-groups (2/2/2/1) — round-20 proven ----
__global__ __launch_bounds__(1024) void k_edge_mfma(
    const float* __restrict__ h, float* __restrict__ e,
    const int* __restrict__ eids, const int* __restrict__ src, const int* __restrict__ dst,
    const unsigned short* __restrict__ w1p, const float* __restrict__ b1,
    const unsigned short* __restrict__ w2p, const float* __restrict__ b2) {
  __shared__ __align__(16) char lds[151040];
  char* W1L = lds;               // 64512 = 9 panels
  char* W2L = lds + 64512;       // 28672
  char* A1  = lds + 93184;       // 40960: [64] rows x 640B bf16, swizzled
  char* A2  = lds + 134144;      // 16384
  int* ss  = (int*)(lds + 150528);
  int* ds_ = (int*)(lds + 150784);
  int tid = threadIdx.x;
  for (int i = tid; i < 4032; i += 1024) ((uint4*)W1L)[i] = ((const uint4*)w1p)[i];
  for (int i = tid; i < 1792; i += 1024) ((uint4*)W2L)[i] = ((const uint4*)w2p)[i];
  // tile-invariant pad zeroing: A1 cols 300..319 and A2 cols 112..127
  if (tid < 320) {
    int row = tid / 5, j = tid % 5;
    uint2 z; z.x = 0u; z.y = 0u;
    *(uint2*)(A1 + SWZ(row, row * 640 + 600 + j * 8)) = z;
  }
  if (tid < 512) {
    int r = tid / 8, c = tid % 8;
    *(unsigned int*)(A2 + SWZ(r, r * 256 + 224 + c * 4)) = 0;
  }

  int lane = tid & 63, w = tid >> 6;   // w in 0..15
  int l15 = lane & 15, lq = lane >> 4;
  int g = w >> 2;                      // wave-group 0..3
  int arow = (w & 3) * 16 + l15;       // 0..63
  int ntb = g * 2, ntc = (g == 3) ? 1 : 2;   // nt range: 2,2,2,1
  f32x4 zero = {0.f, 0.f, 0.f, 0.f};

  for (int tile = blockIdx.x; tile < NT64; tile += gridDim.x) {
    int base = tile * 64;
    if (tid < 64) { int eid = eids[base + tid]; ss[tid] = src[eid]; ds_[tid] = dst[eid]; }
    __syncthreads();   // Bs
    for (int idx = tid; idx < 64 * 25; idx += 1024) {
      int row = idx / 25, c4 = idx % 25;
      float4 f = ((const float4*)e)[(size_t)(base + row) * 25 + c4];
      *(uint2*)(A1 + SWZ(row, row * 640 + 400 + c4 * 8)) = pk4(f);
    }
    for (int idx = tid; idx < 64 * 25; idx += 1024) {
      int row = idx / 25, c4 = idx % 25;
      float4 f = ((const float4*)h)[(size_t)ss[row] * 25 + c4];
      *(uint2*)(A1 + SWZ(row, row * 640 + c4 * 8)) = pk4(f);
    }
    for (int idx = tid; idx < 64 * 25; idx += 1024) {
      int row = idx / 25, c4 = idx % 25;
      float4 f = ((const float4*)h)[(size_t)ds_[row] * 25 + c4];
      *(uint2*)(A1 + SWZ(row, row * 640 + 200 + c4 * 8)) = pk4(f);
    }
    __syncthreads();   // B0
    // -------- GEMM1: A from A1, B from LDS (ks<9) / global (ks=9) --------
    f32x4 acc[2];
    acc[0] = zero; acc[1] = zero;
    #pragma unroll
    for (int ks = 0; ks < 10; ++ks) {
      bf16x8 a = *(const bf16x8*)(A1 + SWZ(arow, arow * 640 + (ks * 32 + lq * 8) * 2));
      #pragma unroll
      for (int i = 0; i < 2; ++i) {
        if (i < ntc) {
          int nt = ntb + i;
          bf16x8 b = (ks < 9)
            ? *(const bf16x8*)(W1L + ks * 7168 + (nt * 64 + lane) * 16)
            : *(const bf16x8*)(w1p + (size_t)9 * 3584 + (nt * 64 + lane) * 8);
          acc[i] = __builtin_amdgcn_mfma_f32_16x16x32_bf16(a, b, acc[i], 0, 0, 0);
        }
      }
    }
    // ep1: relu(C1+b1) -> A2 bf16
    #pragma unroll
    for (int i = 0; i < 2; ++i) {
      if (i < ntc) {
        int o = (ntb + i) * 16 + l15;
        float bias = (o < HD) ? b1[o] : 0.f;
        #pragma unroll
        for (int ii = 0; ii < 4; ++ii) {
          int r = (w & 3) * 16 + lq * 4 + ii;
          float v = acc[i][ii] + bias;
          v = (o < HD) ? frelu(v) : 0.f;
          *(unsigned short*)(A2 + SWZ(r, r * 256 + o * 2)) = f2bf(v);
        }
      }
    }
    __syncthreads();   // B1
    // -------- GEMM2: A from A2, B from LDS --------
    f32x4 acc2[2];
    acc2[0] = zero; acc2[1] = zero;
    #pragma unroll
    for (int ks = 0; ks < 4; ++ks) {
      bf16x8 a = *(const bf16x8*)(A2 + SWZ(arow, arow * 256 + (ks * 32 + lq * 8) * 2));
      #pragma unroll
      for (int i = 0; i < 2; ++i) {
        if (i < ntc) {
          int nt = ntb + i;
          bf16x8 b = *(const bf16x8*)(W2L + ks * 7168 + (nt * 64 + lane) * 16);
          acc2[i] = __builtin_amdgcn_mfma_f32_16x16x32_bf16(a, b, acc2[i], 0, 0, 0);
        }
      }
    }
    // ep2: e += 0.5*(C2+b2)
    #pragma unroll
    for (int i = 0; i < 2; ++i) {
      if (i < ntc) {
        int o = (ntb + i) * 16 + l15;
        if (o < HD) {
          float bias = b2[o];
          #pragma unroll
          for (int ii = 0; ii < 4; ++ii) {
            int r = (w & 3) * 16 + lq * 4 + ii;
            size_t pp = (size_t)(base + r) * HD + o;
            e[pp] = e[pp] + 0.5f * (acc2[i][ii] + bias);
          }
        }
      }
    }
    __syncthreads();   // B2
  }
}

// ---- layer-2 + final MLP fused: 1024 thr / 16 waves; B3 removed; tail 16 lanes/edge ----
__global__ __launch_bounds__(1024) void k_edge_final_mfma(
    const float* __restrict__ h, const float* __restrict__ e,
    const int* __restrict__ eids, const int* __restrict__ src, const int* __restrict__ dst,
    const unsigned short* __restrict__ w1p, const float* __restrict__ b1,
    const unsigned short* __restrict__ w2p, const float* __restrict__ b2,
    const unsigned short* __restrict__ wf1p, const float* __restrict__ fb1,
    const float* __restrict__ fw2, const float* __restrict__ fb2,
    const float* __restrict__ fw3, const float* __restrict__ fb3,
    float* __restrict__ out) {
  __shared__ __align__(16) char lds[156500];
  char* W1L = lds;                       // 64512 = 9 panels
  char* W2L = lds + 64512;               // 28672
  char* A1  = lds + 93184;               // 40960
  char* A2  = lds + 134144;              // 16384: GEMM2-A ; later t fp32 [64][52]
  float* W2s = (float*)(lds + 150528);   // 1250
  float* b2s = (float*)(lds + 155528);   // 25
  float* W3s = (float*)(lds + 155628);   // 25
  float* b3s = (float*)(lds + 155728);   // 1
  int* es  = (int*)(lds + 155732);
  int* ss  = (int*)(lds + 155988);
  int* ds_ = (int*)(lds + 156244);
  int tid = threadIdx.x;
  for (int i = tid; i < 4032; i += 1024) ((uint4*)W1L)[i] = ((const uint4*)w1p)[i];
  for (int i = tid; i < 1792; i += 1024) ((uint4*)W2L)[i] = ((const uint4*)w2p)[i];
  for (int i = tid; i < 1250; i += 1024) W2s[i] = fw2[i];
  if (tid < 25) { b2s[tid] = fb2[tid]; W3s[tid] = fw3[tid]; }
  if (tid == 0) b3s[0] = fb3[0];
  // tile-invariant A1 pad zero (cols 300..319): once
  if (tid < 320) {
    int row = tid / 5, j = tid % 5;
    uint2 z; z.x = 0u; z.y = 0u;
    *(uint2*)(A1 + SWZ(row, row * 640 + 600 + j * 8)) = z;
  }

  int lane = tid & 63, w = tid >> 6;
  int l15 = lane & 15, lq = lane >> 4;
  int g = w >> 2;                      // 0..3
  int arow = (w & 3) * 16 + l15;
  int ntb = g * 2, ntc = (g == 3) ? 1 : 2;
  f32x4 zero = {0.f, 0.f, 0.f, 0.f};

  for (int tile = blockIdx.x; tile < NT64; tile += gridDim.x) {
    int base = tile * 64;
    if (tid < 64) {
      int eid = eids[base + tid];
      es[tid] = eid; ss[tid] = src[eid]; ds_[tid] = dst[eid];
    }
    __syncthreads();   // Bs
    for (int idx = tid; idx < 64 * 25; idx += 1024) {
      int row = idx / 25, c4 = idx % 25;
      float4 f = ((const float4*)e)[(size_t)(base + row) * 25 + c4];
      *(uint2*)(A1 + SWZ(row, row * 640 + 400 + c4 * 8)) = pk4(f);
    }
    for (int idx = tid; idx < 64 * 25; idx += 1024) {
      int row = idx / 25, c4 = idx % 25;
      float4 f = ((const float4*)h)[(size_t)ss[row] * 25 + c4];
      *(uint2*)(A1 + SWZ(row, row * 640 + c4 * 8)) = pk4(f);
    }
    for (int idx = tid; idx < 64 * 25; idx += 1024) {
      int row = idx / 25, c4 = idx % 25;
      float4 f = ((const float4*)h)[(size_t)ds_[row] * 25 + c4];
      *(uint2*)(A1 + SWZ(row, row * 640 + 200 + c4 * 8)) = pk4(f);
    }
    __syncthreads();   // B0
    // -------- GEMM1 --------
    f32x4 acc[2];
    acc[0] = zero; acc[1] = zero;
    #pragma unroll
    for (int ks = 0; ks < 10; ++ks) {
      bf16x8 a = *(const bf16x8*)(A1 + SWZ(arow, arow * 640 + (ks * 32 + lq * 8) * 2));
      #pragma unroll
      for (int i = 0; i < 2; ++i) {
        if (i < ntc) {
          int nt = ntb + i;
          bf16x8 b = (ks < 9)
            ? *(const bf16x8*)(W1L + ks * 7168 + (nt * 64 + lane) * 16)
            : *(const bf16x8*)(w1p + (size_t)9 * 3584 + (nt * 64 + lane) * 8);
          acc[i] = __builtin_amdgcn_mfma_f32_16x16x32_bf16(a, b, acc[i], 0, 0, 0);
        }
      }
    }
    // ep1 -> A2 (cols 0..111); pad cols 112..127 re-zeroed per tile (t clobbers)
    #pragma unroll
    for (int i = 0; i < 2; ++i) {
      if (i < ntc) {
        int o = (ntb + i) * 16 + l15;
        float bias = (o < HD) ? b1[o] : 0.f;
        #pragma unroll
        for (int ii = 0; ii < 4; ++ii) {
          int r = (w & 3) * 16 + lq * 4 + ii;
          float v = acc[i][ii] + bias;
          v = (o < HD) ? frelu(v) : 0.f;
          *(unsigned short*)(A2 + SWZ(r, r * 256 + o * 2)) = f2bf(v);
        }
      }
    }
    if (tid < 512) {
      int r = tid / 8, c = tid % 8;
      *(unsigned int*)(A2 + SWZ(r, r * 256 + 224 + c * 4)) = 0;
    }
    __syncthreads();   // B1
    // -------- GEMM2 --------
    f32x4 acc2[2];
    acc2[0] = zero; acc2[1] = zero;
    #pragma unroll
    for (int ks = 0; ks < 4; ++ks) {
      bf16x8 a = *(const bf16x8*)(A2 + SWZ(arow, arow * 256 + (ks * 32 + lq * 8) * 2));
      #pragma unroll
      for (int i = 0; i < 2; ++i) {
        if (i < ntc) {
          int nt = ntb + i;
          bf16x8 b = *(const bf16x8*)(W2L + ks * 7168 + (nt * 64 + lane) * 16);
          acc2[i] = __builtin_amdgcn_mfma_f32_16x16x32_bf16(a, b, acc2[i], 0, 0, 0);
        }
      }
    }
    // ep2: e_new = e + 0.5*(C2+b2) -> bf16 back into A1 cols 200..299
    #pragma unroll
    for (int i = 0; i < 2; ++i) {
      if (i < ntc) {
        int o = (ntb + i) * 16 + l15;
        if (o < HD) {
          float bias = b2[o];
          #pragma unroll
          for (int ii = 0; ii < 4; ++ii) {
            int r = (w & 3) * 16 + lq * 4 + ii;
            float ne = e[(size_t)(base + r) * HD + o] + 0.5f * (acc2[i][ii] + bias);
            *(unsigned short*)(A1 + SWZ(r, r * 640 + (200 + o) * 2)) = f2bf(ne);
          }
        }
      }
    }
    __syncthreads();   // B2: A1 e_new ready; all A2 (GEMM2) reads drained
    // -------- GEMM3 (final L1): reads A1 only; t-writes go to A2 (disjoint -> no barrier) --------
    f32x4 acc3 = zero;
    #pragma unroll
    for (int ks = 0; ks < 10; ++ks) {
      bf16x8 a = *(const bf16x8*)(A1 + SWZ(arow, arow * 640 + (ks * 32 + lq * 8) * 2));
      bf16x8 b = *(const bf16x8*)(wf1p + ((size_t)(ks * 4 + g) * 64 + lane) * 8);
      acc3 = __builtin_amdgcn_mfma_f32_16x16x32_bf16(a, b, acc3, 0, 0, 0);
    }
    // t = relu(C3+fb1) fp32 [64][52] stride 208 in A2 region (B3 removed: disjoint buffers)
    {
      int o = g * 16 + l15;
      if (o < 50) {
        float bias = fb1[o];
        #pragma unroll
        for (int ii = 0; ii < 4; ++ii) {
          int r = (w & 3) * 16 + lq * 4 + ii;
          *(float*)(A2 + r * 208 + o * 4) = frelu(acc3[ii] + bias);
        }
      }
    }
    __syncthreads();   // B4: t ready
    // fp32 tail: ALL 1024 threads, 16 lanes per edge, 50->25->1
    {
      int elg = tid >> 4, q16 = tid & 15;
      const float* trow = (const float*)(A2 + elg * 208);
      float s0 = b2s[q16 < 25 ? q16 : 0];
      bool has0 = (q16 < 25);
      bool has1 = (16 + q16 < 25);
      float s1 = has1 ? b2s[16 + q16] : 0.f;
      if (!has0) s0 = 0.f;
      for (int k = 0; k < 50; ++k) {
        float tv = trow[k];
        if (has0) s0 = fmaf(tv, W2s[k * 25 + q16], s0);
        if (has1) s1 = fmaf(tv, W2s[k * 25 + 16 + q16], s1);
      }
      float racc = 0.f;
      if (has0) racc = fmaf(frelu(s0), W3s[q16], racc);
      if (has1) racc = fmaf(frelu(s1), W3s[16 + q16], racc);
      racc += __shfl_xor(racc, 1, 16);
      racc += __shfl_xor(racc, 2, 16);
      racc += __shfl_xor(racc, 4, 16);
      racc += __shfl_xor(racc, 8, 16);
      if (q16 == 0) out[es[elg]] = racc + b3s[0];
    }
    __syncthreads();   // B5
  }
}

extern "C" void kernel_launch(void* const* d_in, const int* in_sizes, int n_in,
                              void* d_out, int out_size, void* d_ws, size_t ws_size,
                              hipStream_t stream) {
  (void)in_sizes; (void)n_in; (void)out_size; (void)ws_size;
  const float* x       = (const float*)d_in[0];
  const int*   eidx    = (const int*)  d_in[1];
  const float* eattr   = (const float*)d_in[2];
  const float* node_w  = (const float*)d_in[3];
  const float* node_b  = (const float*)d_in[4];
  const float* edge_w  = (const float*)d_in[5];
  const float* edge_b  = (const float*)d_in[6];
  const float* conv_w1 = (const float*)d_in[7];
  const float* conv_b1 = (const float*)d_in[8];
  const float* conv_w2 = (const float*)d_in[9];
  const float* conv_b2 = (const float*)d_in[10];
  const float* bn_g    = (const float*)d_in[11];
  const float* bn_b    = (const float*)d_in[12];
  const float* em_w1   = (const float*)d_in[13];
  const float* em_b1   = (const float*)d_in[14];
  const float* em_w2   = (const float*)d_in[15];
  const float* em_b2   = (const float*)d_in[16];
  const float* mlp_w1  = (const float*)d_in[17];
  const float* mlp_b1  = (const float*)d_in[18];
  const float* mlp_w2  = (const float*)d_in[19];
  const float* mlp_b2  = (const float*)d_in[20];
  const float* mlp_w3  = (const float*)d_in[21];
  const float* mlp_b3  = (const float*)d_in[22];

  const int* src = eidx;
  const int* dst = eidx + NE;

  // ws layout (max 202.25 MB; ws_size >= 203 MB proven in rounds 5-20)
  char* ws = (char*)d_ws;
  float* h    = (float*)(ws);                     // 20,000,000
  float* e    = (float*)(ws + 40000000);          // 160,000,000 (PERMUTED rows)
  unsigned short* w1p0 = (unsigned short*)(ws + 200000000);  // 71,680
  unsigned short* w1p1 = (unsigned short*)(ws + 200071680);  // 71,680
  unsigned short* w2p0 = (unsigned short*)(ws + 200143360);  // 28,672
  unsigned short* w2p1 = (unsigned short*)(ws + 200172032);  // 28,672
  unsigned short* wf1p = (unsigned short*)(ws + 200200704);  // 40,960 -> ends 200,241,664
  int* rowptr = (int*)(ws + 200241664);           // 50,001 ints (+pad)
  int* cursor = (int*)(ws + 200442112);           // 50,000 ints
  int* eids   = (int*)(ws + 200642112);           // 400,000 ints
  int* part   = (int*)(ws + 202242112);           // 256 ints -> ends 202,243,136

  const int SCAN_NB = (NN + 256) / 256;
  // CSR build (dst-sorted permutation)
  hipMemsetAsync(cursor, 0, (size_t)NN * 4, stream);
  k_hist<<<(NE + 255) / 256, 256, 0, stream>>>(dst, cursor);
  k_scan_part<<<SCAN_NB, 256, 0, stream>>>(cursor, part);
  k_scan_top<<<1, 256, 0, stream>>>(part, SCAN_NB);
  k_scan_fill<<<SCAN_NB, 256, 0, stream>>>(cursor, part, rowptr, cursor);
  k_fill<<<(NE + 255) / 256, 256, 0, stream>>>(dst, cursor, eids);

  // all weight packs in one launch
  k_pack_all<<<(15104 + 255) / 256, 256, 0, stream>>>(
      em_w1, em_w2, mlp_w1, w1p0, w1p1, w2p0, w2p1, wf1p);

  k_node_embed<<<(NN * HD + 255) / 256, 256, 0, stream>>>(x, node_w, node_b, h);
  {
    long long th = (long long)NE * 25;
    k_edge_embed_perm<<<(unsigned)((th + 255) / 256), 256, 0, stream>>>(eattr, eids, edge_w, edge_b, e);
  }

  for (int i = 0; i < 2; ++i) {
    k_gather_node<<<(NN + 63) / 64, 256, 0, stream>>>(
        h, e, rowptr, eids, src,
        conv_w1 + i * HD * HD, conv_b1 + i * HD,
        conv_w2 + i * HD * HD, conv_b2 + i * HD, bn_g + i * HD, bn_b + i * HD);
    if (i == 0) {
      k_edge_mfma<<<256, 1024, 0, stream>>>(
          h, e, eids, src, dst, w1p0, em_b1, w2p0, em_b2);
    } else {
      k_edge_final_mfma<<<256, 1024, 0, stream>>>(
          h, e, eids, src, dst, w1p1, em_b1 + HD, w2p1, em_b2 + HD,
          wf1p, mlp_b1, mlp_w2, mlp_b2, mlp_w3, mlp_b3, (float*)d_out);
    }
  }
}

// Round 22
// 746.776 us; speedup vs baseline: 2.2431x; 2.2431x over previous
//
#include <hip/hip_runtime.h>

#define HD 100
#define NF 16
#define EF 8
#define NN 50000
#define NE 400000
#define NT64 6250   // NE/64 tiles

typedef __attribute__((ext_vector_type(8))) short bf16x8;
typedef __attribute__((ext_vector_type(4))) float f32x4;

__device__ __forceinline__ float frelu(float v) { return v > 0.f ? v : 0.f; }
__device__ __forceinline__ unsigned short f2bf(float f) {
  unsigned int u = __float_as_uint(f);
  unsigned int r = (u + 0x7FFF + ((u >> 16) & 1)) >> 16;   // RNE
  return (unsigned short)r;
}
// XOR-swizzle: spread bank-aligned rows across 16B slots (G4 / T2)
__device__ __forceinline__ int SWZ(int row, int byte) { return byte ^ ((row & 7) << 4); }
__device__ __forceinline__ float4 L4(const float* p) { return *(const float4*)p; }
__device__ __forceinline__ uint2 pk4(float4 f) {
  uint2 o;
  o.x = (unsigned)f2bf(f.x) | ((unsigned)f2bf(f.y) << 16);
  o.y = (unsigned)f2bf(f.z) | ((unsigned)f2bf(f.w) << 16);
  return o;
}

// ---------------- weight pre-pack: W[K][N] fp32 -> frag-linear bf16 ----------------
__device__ __forceinline__ void pack_one(const float* __restrict__ W,
    unsigned short* __restrict__ out, int K, int N, int NT, int t) {
  int lane = t & 63, nt = (t >> 6) % NT, ks = (t >> 6) / NT;
  int kb = ks * 32 + (lane >> 4) * 8, n = nt * 16 + (lane & 15);
  unsigned short v[8];
  #pragma unroll
  for (int j = 0; j < 8; ++j) {
    int k = kb + j;
    float f = (k < K && n < N) ? W[(size_t)k * N + n] : 0.f;
    v[j] = f2bf(f);
  }
  uint4 o4;
  o4.x = (unsigned)v[0] | ((unsigned)v[1] << 16);
  o4.y = (unsigned)v[2] | ((unsigned)v[3] << 16);
  o4.z = (unsigned)v[4] | ((unsigned)v[5] << 16);
  o4.w = (unsigned)v[6] | ((unsigned)v[7] << 16);
  *(uint4*)&out[(size_t)t * 8] = o4;
}

// one launch packs all 5 weight matrices (both layers' W1/W2 + final W1)
__global__ __launch_bounds__(256) void k_pack_all(
    const float* __restrict__ em_w1, const float* __restrict__ em_w2,
    const float* __restrict__ mlp_w1,
    unsigned short* __restrict__ w1p0, unsigned short* __restrict__ w1p1,
    unsigned short* __restrict__ w2p0, unsigned short* __restrict__ w2p1,
    unsigned short* __restrict__ wf1p) {
  int t = blockIdx.x * 256 + threadIdx.x;
  if (t < 4480)        pack_one(em_w1,          w1p0, 300, 100, 7, t);
  else if (t < 8960)   pack_one(em_w1 + 30000,  w1p1, 300, 100, 7, t - 4480);
  else if (t < 10752)  pack_one(em_w2,          w2p0, 100, 100, 7, t - 8960);
  else if (t < 12544)  pack_one(em_w2 + 10000,  w2p1, 100, 100, 7, t - 10752);
  else if (t < 15104)  pack_one(mlp_w1,         wf1p, 300, 50, 4, t - 12544);
}

__global__ __launch_bounds__(256) void k_node_embed(const float* __restrict__ x,
    const float* __restrict__ w, const float* __restrict__ b, float* __restrict__ h) {
  int t = blockIdx.x * 256 + threadIdx.x;
  int n = t / HD, o = t % HD;
  if (n >= NN) return;
  float acc = b[o];
  #pragma unroll
  for (int k = 0; k < NF; ++k) acc = fmaf(x[n * NF + k], w[k * HD + o], acc);
  h[(size_t)n * HD + o] = acc;
}

// e stored in PERMUTED (dst-sorted) layout
__global__ __launch_bounds__(256) void k_edge_embed_perm(const float* __restrict__ ea,
    const int* __restrict__ eids, const float* __restrict__ w, const float* __restrict__ b,
    float* __restrict__ e) {
  __shared__ float ws_[EF * HD];
  __shared__ float bs_[HD];
  int tid = threadIdx.x;
  for (int i = tid; i < EF * HD; i += 256) ws_[i] = w[i];
  for (int i = tid; i < HD; i += 256) bs_[i] = b[i];
  __syncthreads();
  long long t = (long long)blockIdx.x * 256 + tid;
  int p = (int)(t / 25), c4 = (int)(t % 25);
  if (p >= NE) return;
  int eid = eids[p];
  const float* ap = ea + (size_t)eid * EF;
  float4 a0 = L4(ap), a1 = L4(ap + 4);
  float av[8] = {a0.x, a0.y, a0.z, a0.w, a1.x, a1.y, a1.z, a1.w};
  int c0 = c4 * 4;
  float o0 = bs_[c0], o1 = bs_[c0 + 1], o2 = bs_[c0 + 2], o3 = bs_[c0 + 3];
  #pragma unroll
  for (int k = 0; k < EF; ++k) {
    const float* wr = &ws_[k * HD + c0];
    o0 = fmaf(av[k], wr[0], o0); o1 = fmaf(av[k], wr[1], o1);
    o2 = fmaf(av[k], wr[2], o2); o3 = fmaf(av[k], wr[3], o3);
  }
  float4 o; o.x = o0; o.y = o1; o.z = o2; o.w = o3;
  ((float4*)e)[(size_t)p * 25 + c4] = o;
}

// ---------------- CSR build ----------------
__global__ __launch_bounds__(256) void k_hist(const int* __restrict__ dst, int* __restrict__ deg) {
  int eid = blockIdx.x * 256 + threadIdx.x;
  if (eid < NE) atomicAdd(&deg[dst[eid]], 1);
}
__global__ __launch_bounds__(256) void k_scan_part(const int* __restrict__ deg, int* __restrict__ part) {
  __shared__ int sm[256];
  int i = blockIdx.x * 256 + threadIdx.x;
  sm[threadIdx.x] = (i < NN) ? deg[i] : 0;
  __syncthreads();
  for (int s = 128; s > 0; s >>= 1) {
    if (threadIdx.x < s) sm[threadIdx.x] += sm[threadIdx.x + s];
    __syncthreads();
  }
  if (threadIdx.x == 0) part[blockIdx.x] = sm[0];
}
__global__ __launch_bounds__(256) void k_scan_top(int* __restrict__ part, int nb) {
  __shared__ int sm[256];
  int v = (threadIdx.x < nb) ? part[threadIdx.x] : 0;
  sm[threadIdx.x] = v;
  __syncthreads();
  for (int off = 1; off < 256; off <<= 1) {
    int t = (threadIdx.x >= (unsigned)off) ? sm[threadIdx.x - off] : 0;
    __syncthreads();
    sm[threadIdx.x] += t;
    __syncthreads();
  }
  if (threadIdx.x < nb) part[threadIdx.x] = sm[threadIdx.x] - v;  // exclusive
}
// writes BOTH rowptr and cursor (cursor = rowptr[0..NN-1])
__global__ __launch_bounds__(256) void k_scan_fill(const int* __restrict__ deg,
    const int* __restrict__ part, int* __restrict__ rowptr, int* __restrict__ cursor) {
  __shared__ int sm[256];
  int i = blockIdx.x * 256 + threadIdx.x;
  int v = (i < NN) ? deg[i] : 0;
  sm[threadIdx.x] = v;
  __syncthreads();
  for (int off = 1; off < 256; off <<= 1) {
    int t = (threadIdx.x >= (unsigned)off) ? sm[threadIdx.x - off] : 0;
    __syncthreads();
    sm[threadIdx.x] += t;
    __syncthreads();
  }
  int pfx = part[blockIdx.x] + sm[threadIdx.x] - v;  // exclusive prefix
  if (i <= NN) rowptr[i] = pfx;
  if (i < NN) cursor[i] = pfx;
}
__global__ __launch_bounds__(256) void k_fill(const int* __restrict__ dst,
    int* __restrict__ cursor, int* __restrict__ eids) {
  int eid = blockIdx.x * 256 + threadIdx.x;
  if (eid >= NE) return;
  int pos = atomicAdd(&cursor[dst[eid]], 1);
  eids[pos] = eid;
}

// ---- FUSED gather + node update (round-17 proven) ----
__global__ __launch_bounds__(256) void k_gather_node(
    float* __restrict__ h, const float* __restrict__ e,
    const int* __restrict__ rowptr, const int* __restrict__ eids,
    const int* __restrict__ src,
    const float* __restrict__ w1, const float* __restrict__ b1,
    const float* __restrict__ w2, const float* __restrict__ b2,
    const float* __restrict__ gamma, const float* __restrict__ beta) {
  __shared__ float zs[64 * 101];
  int tid = threadIdx.x;
  int base = blockIdx.x * 64;
  {
    int slot = tid >> 2, sub = tid & 3;
    int n = base + slot;
    int cn = n < NN ? n : NN - 1;
    int r0 = rowptr[cn], r1 = rowptr[cn + 1];
    float4 acc[7];
    #pragma unroll
    for (int i = 0; i < 7; ++i) { acc[i].x = 0.f; acc[i].y = 0.f; acc[i].z = 0.f; acc[i].w = 0.f; }
    for (int p = r0; p < r1; ++p) {
      int s = src[eids[p]];
      const float4* hp = (const float4*)&h[(size_t)s * HD];
      const float4* ep = (const float4*)&e[(size_t)p * HD];
      #pragma unroll
      for (int i = 0; i < 7; ++i) {
        int c = sub + i * 4;
        if (c < 25) {
          float4 hv = hp[c], ev = ep[c];
          acc[i].x += frelu(hv.x + ev.x);
          acc[i].y += frelu(hv.y + ev.y);
          acc[i].z += frelu(hv.z + ev.z);
          acc[i].w += frelu(hv.w + ev.w);
        }
      }
    }
    const float4* hn = (const float4*)&h[(size_t)cn * HD];
    #pragma unroll
    for (int i = 0; i < 7; ++i) {
      int c = sub + i * 4;
      if (c < 25) {
        float4 hv = hn[c];
        float* zp = &zs[slot * 101 + c * 4];
        zp[0] = hv.x + acc[i].x;
        zp[1] = hv.y + acc[i].y;
        zp[2] = hv.z + acc[i].z;
        zp[3] = hv.w + acc[i].w;
      }
    }
  }
  __syncthreads();
  int el = tid & 63;
  int o0 = __builtin_amdgcn_readfirstlane((tid >> 6) * 25);
  float* row = &zs[el * 101];
  float acc[25];
  #pragma unroll
  for (int j = 0; j < 25; ++j) acc[j] = b1[o0 + j];
  for (int k = 0; k < HD; ++k) {
    float a = row[k];
    const float* wr = &w1[k * HD + o0];
    #pragma unroll
    for (int j = 0; j < 25; ++j) acc[j] = fmaf(a, wr[j], acc[j]);
  }
  __syncthreads();
  #pragma unroll
  for (int j = 0; j < 25; ++j) row[o0 + j] = frelu(acc[j]);
  __syncthreads();
  float acc2[25];
  #pragma unroll
  for (int j = 0; j < 25; ++j) acc2[j] = b2[o0 + j];
  for (int k = 0; k < HD; ++k) {
    float a = row[k];
    const float* wr = &w2[k * HD + o0];
    #pragma unroll
    for (int j = 0; j < 25; ++j) acc2[j] = fmaf(a, wr[j], acc2[j]);
  }
  int gn = base + el;
  if (gn < NN) {
    const float bninv = 0.99999500003749973f;  // 1/sqrt(1+1e-5)
    #pragma unroll
    for (int j = 0; j < 25; ++j) {
      int o = o0 + j;
      float bn = acc2[j] * (gamma[o] * bninv) + beta[o];
      h[(size_t)gn * HD + o] = (h[(size_t)gn * HD + o] + frelu(bn)) * 0.5f;
    }
  }
}

// ---- layer-1 edge update: 1024 thr / 16 waves, 4 N-groups (2/2/2/1) — round-20 proven ----
__global__ __launch_bounds__(1024) void k_edge_mfma(
    const float* __restrict__ h, float* __restrict__ e,
    const int* __restrict__ eids, const int* __restrict__ src, const int* __restrict__ dst,
    const unsigned short* __restrict__ w1p, const float* __restrict__ b1,
    const unsigned short* __restrict__ w2p, const float* __restrict__ b2) {
  __shared__ __align__(16) char lds[151040];
  char* W1L = lds;               // 64512 = 9 panels
  char* W2L = lds + 64512;       // 28672
  char* A1  = lds + 93184;       // 40960: [64] rows x 640B bf16, swizzled
  char* A2  = lds + 134144;      // 16384
  int* ss  = (int*)(lds + 150528);
  int* ds_ = (int*)(lds + 150784);
  int tid = threadIdx.x;
  for (int i = tid; i < 4032; i += 1024) ((uint4*)W1L)[i] = ((const uint4*)w1p)[i];
  for (int i = tid; i < 1792; i += 1024) ((uint4*)W2L)[i] = ((const uint4*)w2p)[i];
  // tile-invariant pad zeroing: A1 cols 300..319 and A2 cols 112..127
  if (tid < 320) {
    int row = tid / 5, j = tid % 5;
    uint2 z; z.x = 0u; z.y = 0u;
    *(uint2*)(A1 + SWZ(row, row * 640 + 600 + j * 8)) = z;
  }
  if (tid < 512) {
    int r = tid / 8, c = tid % 8;
    *(unsigned int*)(A2 + SWZ(r, r * 256 + 224 + c * 4)) = 0;
  }

  int lane = tid & 63, w = tid >> 6;   // w in 0..15
  int l15 = lane & 15, lq = lane >> 4;
  int g = w >> 2;                      // wave-group 0..3
  int arow = (w & 3) * 16 + l15;       // 0..63
  int ntb = g * 2, ntc = (g == 3) ? 1 : 2;   // nt range: 2,2,2,1
  f32x4 zero = {0.f, 0.f, 0.f, 0.f};

  for (int tile = blockIdx.x; tile < NT64; tile += gridDim.x) {
    int base = tile * 64;
    if (tid < 64) { int eid = eids[base + tid]; ss[tid] = src[eid]; ds_[tid] = dst[eid]; }
    __syncthreads();   // Bs
    for (int idx = tid; idx < 64 * 25; idx += 1024) {
      int row = idx / 25, c4 = idx % 25;
      float4 f = ((const float4*)e)[(size_t)(base + row) * 25 + c4];
      *(uint2*)(A1 + SWZ(row, row * 640 + 400 + c4 * 8)) = pk4(f);
    }
    for (int idx = tid; idx < 64 * 25; idx += 1024) {
      int row = idx / 25, c4 = idx % 25;
      float4 f = ((const float4*)h)[(size_t)ss[row] * 25 + c4];
      *(uint2*)(A1 + SWZ(row, row * 640 + c4 * 8)) = pk4(f);
    }
    for (int idx = tid; idx < 64 * 25; idx += 1024) {
      int row = idx / 25, c4 = idx % 25;
      float4 f = ((const float4*)h)[(size_t)ds_[row] * 25 + c4];
      *(uint2*)(A1 + SWZ(row, row * 640 + 200 + c4 * 8)) = pk4(f);
    }
    __syncthreads();   // B0
    // -------- GEMM1: A from A1, B from LDS (ks<9) / global (ks=9) --------
    f32x4 acc[2];
    acc[0] = zero; acc[1] = zero;
    #pragma unroll
    for (int ks = 0; ks < 10; ++ks) {
      bf16x8 a = *(const bf16x8*)(A1 + SWZ(arow, arow * 640 + (ks * 32 + lq * 8) * 2));
      #pragma unroll
      for (int i = 0; i < 2; ++i) {
        if (i < ntc) {
          int nt = ntb + i;
          bf16x8 b = (ks < 9)
            ? *(const bf16x8*)(W1L + ks * 7168 + (nt * 64 + lane) * 16)
            : *(const bf16x8*)(w1p + (size_t)9 * 3584 + (nt * 64 + lane) * 8);
          acc[i] = __builtin_amdgcn_mfma_f32_16x16x32_bf16(a, b, acc[i], 0, 0, 0);
        }
      }
    }
    // ep1: relu(C1+b1) -> A2 bf16
    #pragma unroll
    for (int i = 0; i < 2; ++i) {
      if (i < ntc) {
        int o = (ntb + i) * 16 + l15;
        float bias = (o < HD) ? b1[o] : 0.f;
        #pragma unroll
        for (int ii = 0; ii < 4; ++ii) {
          int r = (w & 3) * 16 + lq * 4 + ii;
          float v = acc[i][ii] + bias;
          v = (o < HD) ? frelu(v) : 0.f;
          *(unsigned short*)(A2 + SWZ(r, r * 256 + o * 2)) = f2bf(v);
        }
      }
    }
    __syncthreads();   // B1
    // -------- GEMM2: A from A2, B from LDS --------
    f32x4 acc2[2];
    acc2[0] = zero; acc2[1] = zero;
    #pragma unroll
    for (int ks = 0; ks < 4; ++ks) {
      bf16x8 a = *(const bf16x8*)(A2 + SWZ(arow, arow * 256 + (ks * 32 + lq * 8) * 2));
      #pragma unroll
      for (int i = 0; i < 2; ++i) {
        if (i < ntc) {
          int nt = ntb + i;
          bf16x8 b = *(const bf16x8*)(W2L + ks * 7168 + (nt * 64 + lane) * 16);
          acc2[i] = __builtin_amdgcn_mfma_f32_16x16x32_bf16(a, b, acc2[i], 0, 0, 0);
        }
      }
    }
    // ep2: e += 0.5*(C2+b2)
    #pragma unroll
    for (int i = 0; i < 2; ++i) {
      if (i < ntc) {
        int o = (ntb + i) * 16 + l15;
        if (o < HD) {
          float bias = b2[o];
          #pragma unroll
          for (int ii = 0; ii < 4; ++ii) {
            int r = (w & 3) * 16 + lq * 4 + ii;
            size_t pp = (size_t)(base + r) * HD + o;
            e[pp] = e[pp] + 0.5f * (acc2[i][ii] + bias);
          }
        }
      }
    }
    __syncthreads();   // B2
  }
}

// ---- layer-2 + final MLP fused: 1024 thr / 16 waves, 4 N-groups — round-20 proven ----
__global__ __launch_bounds__(1024) void k_edge_final_mfma(
    const float* __restrict__ h, const float* __restrict__ e,
    const int* __restrict__ eids, const int* __restrict__ src, const int* __restrict__ dst,
    const unsigned short* __restrict__ w1p, const float* __restrict__ b1,
    const unsigned short* __restrict__ w2p, const float* __restrict__ b2,
    const unsigned short* __restrict__ wf1p, const float* __restrict__ fb1,
    const float* __restrict__ fw2, const float* __restrict__ fb2,
    const float* __restrict__ fw3, const float* __restrict__ fb3,
    float* __restrict__ out) {
  __shared__ __align__(16) char lds[156500];
  char* W1L = lds;                       // 64512 = 9 panels
  char* W2L = lds + 64512;               // 28672
  char* A1  = lds + 93184;               // 40960
  char* A2  = lds + 134144;              // 16384: GEMM2-A ; later t fp32 [64][52]
  float* W2s = (float*)(lds + 150528);   // 1250
  float* b2s = (float*)(lds + 155528);   // 25
  float* W3s = (float*)(lds + 155628);   // 25
  float* b3s = (float*)(lds + 155728);   // 1
  int* es  = (int*)(lds + 155732);
  int* ss  = (int*)(lds + 155988);
  int* ds_ = (int*)(lds + 156244);
  int tid = threadIdx.x;
  for (int i = tid; i < 4032; i += 1024) ((uint4*)W1L)[i] = ((const uint4*)w1p)[i];
  for (int i = tid; i < 1792; i += 1024) ((uint4*)W2L)[i] = ((const uint4*)w2p)[i];
  for (int i = tid; i < 1250; i += 1024) W2s[i] = fw2[i];
  if (tid < 25) { b2s[tid] = fb2[tid]; W3s[tid] = fw3[tid]; }
  if (tid == 0) b3s[0] = fb3[0];
  // tile-invariant A1 pad zero (cols 300..319): once
  if (tid < 320) {
    int row = tid / 5, j = tid % 5;
    uint2 z; z.x = 0u; z.y = 0u;
    *(uint2*)(A1 + SWZ(row, row * 640 + 600 + j * 8)) = z;
  }

  int lane = tid & 63, w = tid >> 6;
  int l15 = lane & 15, lq = lane >> 4;
  int g = w >> 2;                      // 0..3
  int arow = (w & 3) * 16 + l15;
  int ntb = g * 2, ntc = (g == 3) ? 1 : 2;
  f32x4 zero = {0.f, 0.f, 0.f, 0.f};

  for (int tile = blockIdx.x; tile < NT64; tile += gridDim.x) {
    int base = tile * 64;
    if (tid < 64) {
      int eid = eids[base + tid];
      es[tid] = eid; ss[tid] = src[eid]; ds_[tid] = dst[eid];
    }
    __syncthreads();   // Bs
    for (int idx = tid; idx < 64 * 25; idx += 1024) {
      int row = idx / 25, c4 = idx % 25;
      float4 f = ((const float4*)e)[(size_t)(base + row) * 25 + c4];
      *(uint2*)(A1 + SWZ(row, row * 640 + 400 + c4 * 8)) = pk4(f);
    }
    for (int idx = tid; idx < 64 * 25; idx += 1024) {
      int row = idx / 25, c4 = idx % 25;
      float4 f = ((const float4*)h)[(size_t)ss[row] * 25 + c4];
      *(uint2*)(A1 + SWZ(row, row * 640 + c4 * 8)) = pk4(f);
    }
    for (int idx = tid; idx < 64 * 25; idx += 1024) {
      int row = idx / 25, c4 = idx % 25;
      float4 f = ((const float4*)h)[(size_t)ds_[row] * 25 + c4];
      *(uint2*)(A1 + SWZ(row, row * 640 + 200 + c4 * 8)) = pk4(f);
    }
    __syncthreads();   // B0
    // -------- GEMM1 --------
    f32x4 acc[2];
    acc[0] = zero; acc[1] = zero;
    #pragma unroll
    for (int ks = 0; ks < 10; ++ks) {
      bf16x8 a = *(const bf16x8*)(A1 + SWZ(arow, arow * 640 + (ks * 32 + lq * 8) * 2));
      #pragma unroll
      for (int i = 0; i < 2; ++i) {
        if (i < ntc) {
          int nt = ntb + i;
          bf16x8 b = (ks < 9)
            ? *(const bf16x8*)(W1L + ks * 7168 + (nt * 64 + lane) * 16)
            : *(const bf16x8*)(w1p + (size_t)9 * 3584 + (nt * 64 + lane) * 8);
          acc[i] = __builtin_amdgcn_mfma_f32_16x16x32_bf16(a, b, acc[i], 0, 0, 0);
        }
      }
    }
    // ep1 -> A2 (cols 0..111); pad cols 112..127 re-zeroed per tile (t clobbers)
    #pragma unroll
    for (int i = 0; i < 2; ++i) {
      if (i < ntc) {
        int o = (ntb + i) * 16 + l15;
        float bias = (o < HD) ? b1[o] : 0.f;
        #pragma unroll
        for (int ii = 0; ii < 4; ++ii) {
          int r = (w & 3) * 16 + lq * 4 + ii;
          float v = acc[i][ii] + bias;
          v = (o < HD) ? frelu(v) : 0.f;
          *(unsigned short*)(A2 + SWZ(r, r * 256 + o * 2)) = f2bf(v);
        }
      }
    }
    if (tid < 512) {
      int r = tid / 8, c = tid % 8;
      *(unsigned int*)(A2 + SWZ(r, r * 256 + 224 + c * 4)) = 0;
    }
    __syncthreads();   // B1
    // -------- GEMM2 --------
    f32x4 acc2[2];
    acc2[0] = zero; acc2[1] = zero;
    #pragma unroll
    for (int ks = 0; ks < 4; ++ks) {
      bf16x8 a = *(const bf16x8*)(A2 + SWZ(arow, arow * 256 + (ks * 32 + lq * 8) * 2));
      #pragma unroll
      for (int i = 0; i < 2; ++i) {
        if (i < ntc) {
          int nt = ntb + i;
          bf16x8 b = *(const bf16x8*)(W2L + ks * 7168 + (nt * 64 + lane) * 16);
          acc2[i] = __builtin_amdgcn_mfma_f32_16x16x32_bf16(a, b, acc2[i], 0, 0, 0);
        }
      }
    }
    // ep2: e_new = e + 0.5*(C2+b2) -> bf16 back into A1 cols 200..299
    #pragma unroll
    for (int i = 0; i < 2; ++i) {
      if (i < ntc) {
        int o = (ntb + i) * 16 + l15;
        if (o < HD) {
          float bias = b2[o];
          #pragma unroll
          for (int ii = 0; ii < 4; ++ii) {
            int r = (w & 3) * 16 + lq * 4 + ii;
            float ne = e[(size_t)(base + r) * HD + o] + 0.5f * (acc2[i][ii] + bias);
            *(unsigned short*)(A1 + SWZ(r, r * 640 + (200 + o) * 2)) = f2bf(ne);
          }
        }
      }
    }
    __syncthreads();   // B2
    // -------- GEMM3 (final L1): A from A1 (h + e_new), WF from global L2; nt = g --------
    f32x4 acc3 = zero;
    #pragma unroll
    for (int ks = 0; ks < 10; ++ks) {
      bf16x8 a = *(const bf16x8*)(A1 + SWZ(arow, arow * 640 + (ks * 32 + lq * 8) * 2));
      bf16x8 b = *(const bf16x8*)(wf1p + ((size_t)(ks * 4 + g) * 64 + lane) * 8);
      acc3 = __builtin_amdgcn_mfma_f32_16x16x32_bf16(a, b, acc3, 0, 0, 0);
    }
    __syncthreads();   // B3
    // t = relu(C3+fb1) fp32 [64][52] stride 208 in A2 region
    {
      int o = g * 16 + l15;
      if (o < 50) {
        float bias = fb1[o];
        #pragma unroll
        for (int ii = 0; ii < 4; ++ii) {
          int r = (w & 3) * 16 + lq * 4 + ii;
          *(float*)(A2 + r * 208 + o * 4) = frelu(acc3[ii] + bias);
        }
      }
    }
    __syncthreads();   // B4
    // fp32 tail: first 512 threads, 8 lanes per edge, 50->25->1
    if (tid < 512) {
      int elg = tid >> 3, q8 = tid & 7;
      const float* trow = (const float*)(A2 + elg * 208);
      float s[4];
      {
        int i = 0;
        #pragma unroll
        for (int j0 = 0; j0 < 25; j0 += 8) { if (j0 + q8 < 25) s[i++] = b2s[j0 + q8]; }
      }
      for (int k = 0; k < 50; ++k) {
        float tv = trow[k];
        int i = 0;
        #pragma unroll
        for (int j0 = 0; j0 < 25; j0 += 8) {
          if (j0 + q8 < 25) { s[i] = fmaf(tv, W2s[k * 25 + j0 + q8], s[i]); ++i; }
        }
      }
      float racc = 0.f;
      {
        int i = 0;
        #pragma unroll
        for (int j0 = 0; j0 < 25; j0 += 8) {
          if (j0 + q8 < 25) { racc = fmaf(frelu(s[i]), W3s[j0 + q8], racc); ++i; }
        }
      }
      racc += __shfl_xor(racc, 1, 8);
      racc += __shfl_xor(racc, 2, 8);
      racc += __shfl_xor(racc, 4, 8);
      if (q8 == 0) out[es[elg]] = racc + b3s[0];
    }
    __syncthreads();   // B5
  }
}

extern "C" void kernel_launch(void* const* d_in, const int* in_sizes, int n_in,
                              void* d_out, int out_size, void* d_ws, size_t ws_size,
                              hipStream_t stream) {
  (void)in_sizes; (void)n_in; (void)out_size; (void)ws_size;
  const float* x       = (const float*)d_in[0];
  const int*   eidx    = (const int*)  d_in[1];
  const float* eattr   = (const float*)d_in[2];
  const float* node_w  = (const float*)d_in[3];
  const float* node_b  = (const float*)d_in[4];
  const float* edge_w  = (const float*)d_in[5];
  const float* edge_b  = (const float*)d_in[6];
  const float* conv_w1 = (const float*)d_in[7];
  const float* conv_b1 = (const float*)d_in[8];
  const float* conv_w2 = (const float*)d_in[9];
  const float* conv_b2 = (const float*)d_in[10];
  const float* bn_g    = (const float*)d_in[11];
  const float* bn_b    = (const float*)d_in[12];
  const float* em_w1   = (const float*)d_in[13];
  const float* em_b1   = (const float*)d_in[14];
  const float* em_w2   = (const float*)d_in[15];
  const float* em_b2   = (const float*)d_in[16];
  const float* mlp_w1  = (const float*)d_in[17];
  const float* mlp_b1  = (const float*)d_in[18];
  const float* mlp_w2  = (const float*)d_in[19];
  const float* mlp_b2  = (const float*)d_in[20];
  const float* mlp_w3  = (const float*)d_in[21];
  const float* mlp_b3  = (const float*)d_in[22];

  const int* src = eidx;
  const int* dst = eidx + NE;

  // ws layout (max 202.25 MB; ws_size >= 203 MB proven in rounds 5-21)
  char* ws = (char*)d_ws;
  float* h    = (float*)(ws);                     // 20,000,000
  float* e    = (float*)(ws + 40000000);          // 160,000,000 (PERMUTED rows)
  unsigned short* w1p0 = (unsigned short*)(ws + 200000000);  // 71,680
  unsigned short* w1p1 = (unsigned short*)(ws + 200071680);  // 71,680
  unsigned short* w2p0 = (unsigned short*)(ws + 200143360);  // 28,672
  unsigned short* w2p1 = (unsigned short*)(ws + 200172032);  // 28,672
  unsigned short* wf1p = (unsigned short*)(ws + 200200704);  // 40,960 -> ends 200,241,664
  int* rowptr = (int*)(ws + 200241664);           // 50,001 ints (+pad)
  int* cursor = (int*)(ws + 200442112);           // 50,000 ints
  int* eids   = (int*)(ws + 200642112);           // 400,000 ints
  int* part   = (int*)(ws + 202242112);           // 256 ints -> ends 202,243,136

  const int SCAN_NB = (NN + 256) / 256;
  // CSR build (dst-sorted permutation)
  hipMemsetAsync(cursor, 0, (size_t)NN * 4, stream);
  k_hist<<<(NE + 255) / 256, 256, 0, stream>>>(dst, cursor);
  k_scan_part<<<SCAN_NB, 256, 0, stream>>>(cursor, part);
  k_scan_top<<<1, 256, 0, stream>>>(part, SCAN_NB);
  k_scan_fill<<<SCAN_NB, 256, 0, stream>>>(cursor, part, rowptr, cursor);
  k_fill<<<(NE + 255) / 256, 256, 0, stream>>>(dst, cursor, eids);

  // all weight packs in one launch
  k_pack_all<<<(15104 + 255) / 256, 256, 0, stream>>>(
      em_w1, em_w2, mlp_w1, w1p0, w1p1, w2p0, w2p1, wf1p);

  k_node_embed<<<(NN * HD + 255) / 256, 256, 0, stream>>>(x, node_w, node_b, h);
  {
    long long th = (long long)NE * 25;
    k_edge_embed_perm<<<(unsigned)((th + 255) / 256), 256, 0, stream>>>(eattr, eids, edge_w, edge_b, e);
  }

  for (int i = 0; i < 2; ++i) {
    k_gather_node<<<(NN + 63) / 64, 256, 0, stream>>>(
        h, e, rowptr, eids, src,
        conv_w1 + i * HD * HD, conv_b1 + i * HD,
        conv_w2 + i * HD * HD, conv_b2 + i * HD, bn_g + i * HD, bn_b + i * HD);
    if (i == 0) {
      k_edge_mfma<<<256, 1024, 0, stream>>>(
          h, e, eids, src, dst, w1p0, em_b1, w2p0, em_b2);
    } else {
      k_edge_final_mfma<<<256, 1024, 0, stream>>>(
          h, e, eids, src, dst, w1p1, em_b1 + HD, w2p1, em_b2 + HD,
          wf1p, mlp_b1, mlp_w2, mlp_b2, mlp_w3, mlp_b3, (float*)d_out);
    }
  }
}